// Round 9
// baseline (634.889 us; speedup 1.0000x reference)
//
#include <hip/hip_runtime.h>
#include <hip/hip_bf16.h>

#define TOK 16384
#define DIM 1024
#define HID 2048
#define NEXP 8

typedef __attribute__((ext_vector_type(4))) float f32x4;
typedef __attribute__((ext_vector_type(8))) short s16x8;

__device__ __forceinline__ unsigned short f2bf(float f) {
  union { float f; unsigned u; } v; v.f = f;
  unsigned r = v.u + 0x7fffu + ((v.u >> 16) & 1u);   // RNE
  return (unsigned short)(r >> 16);
}
// byte offset of element (r, byte-col kk2) inside a [128 rows][128 B] tile, XOR-swizzled
__device__ __forceinline__ int tile_byte(int r, int kk2) {
  return (r * 128 + kk2) ^ ((r & 7) << 4);
}
__device__ __forceinline__ void gld_lds16(const void* g, void* l) {
  __builtin_amdgcn_global_load_lds(
      (const __attribute__((address_space(1))) unsigned int*)g,
      (__attribute__((address_space(3))) unsigned int*)l, 16, 0, 0);
}
// bijective XCD-chunked block remap (m204): physical p (xcd = p%8) -> logical
__device__ __forceinline__ int xcd_swz(int p, int nwg) {
  int q = nwg >> 3, r = nwg & 7;
  int xcd = p & 7, idx = p >> 3;
  return (xcd < r ? xcd * (q + 1) : r * (q + 1) + (xcd - r) * q) + idx;
}

// Wg [D][E] -> WgT [E][D] fp32 (tiny, 32 KB)
__global__ void wg_tr(const float* __restrict__ Wg, float* __restrict__ WgT) {
  int i = blockIdx.x * 256 + threadIdx.x;   // 8192
  int e = i >> 10, dd = i & 1023;
  WgT[i] = Wg[dd * NEXP + e];
}

// ---------------------------------------------------------------------------
// Weight prepass: fp32 src [E][rows][cols] -> bf16 128-wide tiled-swizzled
// dst[e][ct][kb][16KB tile]; tile(r<128, kk<64) = src[e][kb*64+kk][ct*128+r]
// ---------------------------------------------------------------------------
__global__ void prep_tiles(const float* __restrict__ src, unsigned short* __restrict__ dst,
                           int rows, int cols) {
  int ct = blockIdx.x, kb = blockIdx.y, e = blockIdx.z;
  int nct = gridDim.x, nkb = gridDim.y;
  __shared__ __align__(16) unsigned short tile[8192];
  const float* s = src + ((size_t)e * rows + kb * 64) * cols + ct * 128;
  int tid = threadIdx.x;  // 256
  #pragma unroll
  for (int it = 0; it < 8; it++) {
    int idx = it * 256 + tid;          // 2048 float4 chunks
    int kk = idx >> 5;                 // 0..63
    int r4 = (idx & 31) * 4;           // 0..124
    float4 v = *(const float4*)(s + (size_t)kk * cols + r4);
    char* tb = (char*)tile;
    *(unsigned short*)(tb + tile_byte(r4 + 0, kk * 2)) = f2bf(v.x);
    *(unsigned short*)(tb + tile_byte(r4 + 1, kk * 2)) = f2bf(v.y);
    *(unsigned short*)(tb + tile_byte(r4 + 2, kk * 2)) = f2bf(v.z);
    *(unsigned short*)(tb + tile_byte(r4 + 3, kk * 2)) = f2bf(v.w);
  }
  __syncthreads();
  unsigned short* d = dst + (((size_t)e * nct + ct) * nkb + kb) * 8192;
  #pragma unroll
  for (int it = 0; it < 4; it++) {
    int o = it * 256 + tid;
    *(s16x8*)(d + o * 8) = *(const s16x8*)((const char*)tile + o * 16);
  }
}

// ---------------------------------------------------------------------------
// Router phase A (fused x->bf16 convert): fp32 logits via coalesced WgT,
// exact top-2, no atomics.
// ---------------------------------------------------------------------------
__global__ __launch_bounds__(256)
void router_logits_cvt(const float* __restrict__ x, const float* __restrict__ WgT,
                       unsigned short* __restrict__ xbf,
                       int* __restrict__ sel, float2* __restrict__ wp) {
  int wave = threadIdx.x >> 6, lane = threadIdx.x & 63;
  int t = blockIdx.x * 4 + wave;
  const f32x4* xr = (const f32x4*)(x + (size_t)t * DIM);
  unsigned short* xb = xbf + (size_t)t * DIM;
  float acc[NEXP];
  #pragma unroll
  for (int e = 0; e < NEXP; e++) acc[e] = 0.f;
  #pragma unroll
  for (int q = 0; q < 4; q++) {
    f32x4 xv = xr[q * 64 + lane];
    ushort4 bv;
    bv.x = f2bf(xv[0]); bv.y = f2bf(xv[1]); bv.z = f2bf(xv[2]); bv.w = f2bf(xv[3]);
    *(ushort4*)(xb + (q * 64 + lane) * 4) = bv;
    #pragma unroll
    for (int e = 0; e < NEXP; e++) {
      f32x4 wv = *(const f32x4*)(WgT + (size_t)e * DIM + (q * 64 + lane) * 4);
      acc[e] = fmaf(xv[3], wv[3], fmaf(xv[2], wv[2], fmaf(xv[1], wv[1], fmaf(xv[0], wv[0], acc[e]))));
    }
  }
  #pragma unroll
  for (int e = 0; e < NEXP; e++) {
    float v = acc[e];
    #pragma unroll
    for (int off = 32; off >= 1; off >>= 1) v += __shfl_xor(v, off);
    acc[e] = v;
  }
  if (lane == 0) {
    float m = acc[0];
    #pragma unroll
    for (int e = 1; e < NEXP; e++) m = fmaxf(m, acc[e]);
    float p[NEXP], s = 0.f;
    #pragma unroll
    for (int e = 0; e < NEXP; e++) { p[e] = expf(acc[e] - m); s += p[e]; }
    float inv = 1.f / s;
    int i0 = 0; float v0 = p[0];
    #pragma unroll
    for (int e = 1; e < NEXP; e++) if (p[e] > v0) { v0 = p[e]; i0 = e; }   // strict > = low-index tie-break
    int i1 = -1; float v1 = -1.f;
    #pragma unroll
    for (int e = 0; e < NEXP; e++) if (e != i0 && p[e] > v1) { v1 = p[e]; i1 = e; }
    v0 *= inv; v1 *= inv;
    float den = v0 + v1 + 1e-9f;
    sel[t] = i0 | (i1 << 4);
    wp[t] = make_float2(v0 / den, v1 / den);
  }
}

// ---------------------------------------------------------------------------
// Router phase B: ballot-ranked scatter; 1 atomic per (block,bin).
// ---------------------------------------------------------------------------
__global__ __launch_bounds__(256)
void router_scatter(const int* __restrict__ sel, const float2* __restrict__ wp,
                    int* __restrict__ counts, int* __restrict__ tok_list,
                    float* __restrict__ w_list) {
  __shared__ int lh0[4][16], lh1[4][16];
  __shared__ int bbase[16];
  int tid = threadIdx.x, wave = tid >> 6, lane = tid & 63;
  int t = blockIdx.x * 256 + tid;
  int s = sel[t];
  int b0 = s & 15;
  int b1 = 8 + ((s >> 4) & 15);
  float2 w = wp[t];
  unsigned long long lt = (lane == 63) ? ~0ull >> 1 : (((unsigned long long)1 << lane) - 1);
  int r0 = 0, r1 = 0;
  #pragma unroll
  for (int b = 0; b < 8; b++) {
    unsigned long long m0 = __ballot(b0 == b);
    if (b0 == b) r0 = __popcll(m0 & lt);
    if (lane == 0) { lh0[wave][b] = __popcll(m0); lh1[wave][b] = 0; }
  }
  #pragma unroll
  for (int b = 8; b < 16; b++) {
    unsigned long long m1 = __ballot(b1 == b);
    if (b1 == b) r1 = __popcll(m1 & lt);
    if (lane == 0) { lh1[wave][b] = __popcll(m1); lh0[wave][b] = 0; }
  }
  __syncthreads();
  if (tid < 16) {
    int h = 0;
    #pragma unroll
    for (int v = 0; v < 4; v++) h += lh0[v][tid] + lh1[v][tid];
    bbase[tid] = atomicAdd(&counts[tid], h);
  }
  __syncthreads();
  int p0 = bbase[b0] + r0;
  int p1 = bbase[b1] + r1;
  #pragma unroll
  for (int v = 0; v < 4; v++) {
    if (v < wave) { p0 += lh0[v][b0]; p1 += lh1[v][b1]; }
  }
  int e0 = b0, e1 = b1 - 8;
  tok_list[e0 * TOK + p0] = t;
  w_list[e0 * TOK + p0] = w.x;
  int q1 = TOK - 1 - p1;
  tok_list[e1 * TOK + q1] = t;
  w_list[e1 * TOK + q1] = w.y;
}

// off[e*2+seg] = prefix of 128-padded segment row counts
__global__ void calc_off(const int* __restrict__ counts, int* __restrict__ off) {
  if (threadIdx.x == 0 && blockIdx.x == 0) {
    int a = 0;
    for (int e = 0; e < NEXP; e++)
      for (int s = 0; s < 2; s++) {
        off[e * 2 + s] = a;
        a += (counts[s * 8 + e] + 127) & ~127;
      }
  }
}

// ---------------------------------------------------------------------------
// GEMM1: 128x128 tile, BK=64, 4 waves (2x2), double-buffered LDS with
// COUNTED-vmcnt pipeline (T3+T4): stage(t+1) stays in flight across barriers;
// vmcnt(8) guarantees only stage(t) retired. RAW: each wave drains its own
// t-loads before s_barrier; WAR: trailing s_barrier before buf reuse.
// ---------------------------------------------------------------------------
__global__ __launch_bounds__(256, 2)
void moe_gemm1(const unsigned short* __restrict__ xbf, const unsigned short* __restrict__ w1s,
               const float* __restrict__ b1, const int* __restrict__ counts,
               const int* __restrict__ off, const int* __restrict__ tok_list,
               unsigned short* __restrict__ h_s, int ct_off, int nkbc, int nct) {
  int logical = xcd_swz(blockIdx.x, gridDim.x);
  int ct_l = logical % nct;
  int g = logical / nct;
  int e = -1, seg = 0, rt = 0, segcnt = 0, base = 0;
  #pragma unroll
  for (int zz = 0; zz < 16; zz++) {
    int ee = zz >> 1, ss = zz & 1;
    int c = counts[ss * 8 + ee];
    int nt = (c + 127) >> 7;
    if (e < 0 && g < base + nt) { e = ee; seg = ss; rt = g - base; segcnt = c; }
    base += nt;
  }
  if (e < 0) return;

  __shared__ __align__(16) unsigned short As[2][8192];
  __shared__ __align__(16) unsigned short Bs[2][8192];
  __shared__ int tokS[128];

  int tid = threadIdx.x, wave = tid >> 6, lane = tid & 63;
  int llo = lane & 15, lhi = lane >> 4;
  int wr = wave >> 1, wc = wave & 1;
  int ct_g = ct_off + ct_l;

  if (tid < 128) {
    int q = rt * 128 + tid;
    int qq = q < segcnt ? q : segcnt - 1;       // clamp: dup rows land in hs pad, discarded later
    int slot = seg ? (TOK - 1 - qq) : qq;
    tokS[tid] = tok_list[e * TOK + slot];
  }
  __syncthreads();

  // A sources: linear LDS chunk (i*256+tid) covers (row = i*32 + tid/8, c16 = tid&7);
  // source chunk pre-swizzled so swizzled ds_read gets original bytes (rule #21).
  const char* srcA[4];
  #pragma unroll
  for (int i = 0; i < 4; i++) {
    int r = i * 32 + (tid >> 3);
    srcA[i] = (const char*)xbf + (size_t)tokS[r] * (DIM * 2) + (((tid & 7) ^ (r & 7)) * 16);
  }
  const char* gB = (const char*)(w1s + (((size_t)e * 16 + ct_g) * 16) * 8192);

  f32x4 acc[4][4];
  #pragma unroll
  for (int i = 0; i < 4; i++)
    #pragma unroll
    for (int j = 0; j < 4; j++) acc[i][j] = (f32x4){0.f, 0.f, 0.f, 0.f};

  auto stage = [&](int buf, int kb) {            // 8 vector-mem instrs / thread
    #pragma unroll
    for (int i = 0; i < 4; i++)
      gld_lds16(srcA[i] + kb * 128, (char*)As[buf] + i * 4096 + wave * 1024);
    const char* gs = gB + (size_t)kb * 16384 + wave * 1024 + lane * 16;
    #pragma unroll
    for (int i = 0; i < 4; i++)
      gld_lds16(gs + i * 4096, (char*)Bs[buf] + i * 4096 + wave * 1024);
  };

  stage(0, 0);
  __syncthreads();                               // full drain: buf0 ready
  for (int kb = 0; kb < 16; kb++) {
    int cur = kb & 1;
    if (kb < 15) {
      stage(cur ^ 1, kb + 1);                    // stays in flight across barriers
      asm volatile("s_waitcnt vmcnt(8)" ::: "memory");   // stage(cur) retired
    } else {
      asm volatile("s_waitcnt vmcnt(0)" ::: "memory");
    }
    __builtin_amdgcn_s_barrier();                // all waves' cur-data landed
    __builtin_amdgcn_sched_barrier(0);
    const char* Ab = (const char*)As[cur];
    const char* Bb = (const char*)Bs[cur];
    #pragma unroll
    for (int ks = 0; ks < 2; ks++) {
      s16x8 a[4], b[4];
      #pragma unroll
      for (int f = 0; f < 4; f++) {
        a[f] = *(const s16x8*)(Ab + tile_byte(wr * 64 + f * 16 + llo, ks * 64 + lhi * 16));
        b[f] = *(const s16x8*)(Bb + tile_byte(wc * 64 + f * 16 + llo, ks * 64 + lhi * 16));
      }
      #pragma unroll
      for (int fr = 0; fr < 4; fr++)
        #pragma unroll
        for (int fc = 0; fc < 4; fc++)
          acc[fr][fc] = __builtin_amdgcn_mfma_f32_16x16x32_bf16(a[fr], b[fc], acc[fr][fc], 0, 0, 0);
    }
    __builtin_amdgcn_sched_barrier(0);
    __builtin_amdgcn_s_barrier();                // reads done before buf reuse
  }

  // epilogue: relu(acc + b1) -> hs 128-tiled-swizzled bf16 (chunk-local tiles)
  size_t grt = (size_t)(off[e * 2 + seg] >> 7) + rt;
  unsigned short* hb = h_s + grt * ((size_t)nkbc * 8192);
  const float* b1e = b1 + e * HID + ct_g * 128;
  #pragma unroll
  for (int fc = 0; fc < 4; fc++) {
    int col = wc * 64 + fc * 16 + llo;        // 0..127 within ct
    float bv = b1e[col];
    char* tb = (char*)(hb + ((size_t)(ct_l * 2 + (col >> 6))) * 8192);
    int kk2 = (col & 63) * 2;
    #pragma unroll
    for (int fr = 0; fr < 4; fr++) {
      int r0 = wr * 64 + fr * 16 + lhi * 4;
      #pragma unroll
      for (int j = 0; j < 4; j++) {
        float v = fmaxf(acc[fr][fc][j] + bv, 0.f);
        *(unsigned short*)(tb + tile_byte(r0 + j, kk2)) = f2bf(v);
      }
    }
  }
}

// ---------------------------------------------------------------------------
// GEMM2 (per seg/chunk): y[t] (= | +=) w*(hs @ W2_chunk) [+ w*b2].
// Same counted-vmcnt pipeline; both operands linear gld_lds from pre-swizzled
// 16KB tiles. ct-fastest + XCD chunk swizzle.
// ---------------------------------------------------------------------------
template<int NKBC>
__global__ __launch_bounds__(256, 2)
void moe_gemm2(const unsigned short* __restrict__ h_s, const unsigned short* __restrict__ w2s,
               const float* __restrict__ b2, const int* __restrict__ counts,
               const int* __restrict__ off, const int* __restrict__ tok_list,
               const float* __restrict__ w_list, float* __restrict__ y,
               int seg, int kb_off, int add_b2, int accum) {
  int logical = xcd_swz(blockIdx.x, gridDim.x);
  int ct = logical & 7;       // DIM/128 = 8 column tiles, fastest
  int g = logical >> 3;
  int e = -1, rt = 0, segcnt = 0, base = 0;
  #pragma unroll
  for (int ee = 0; ee < 8; ee++) {
    int c = counts[seg * 8 + ee];
    int nt = (c + 127) >> 7;
    if (e < 0 && g < base + nt) { e = ee; rt = g - base; segcnt = c; }
    base += nt;
  }
  if (e < 0) return;

  __shared__ __align__(16) unsigned short As[2][8192];
  __shared__ __align__(16) unsigned short Bs[2][8192];

  int tid = threadIdx.x, wave = tid >> 6, lane = tid & 63;
  int llo = lane & 15, lhi = lane >> 4;
  int wr = wave >> 1, wc = wave & 1;

  size_t grt = (size_t)(off[e * 2 + seg] >> 7) + rt;
  const char* gA = (const char*)(h_s + grt * ((size_t)NKBC * 8192));
  const char* gB = (const char*)(w2s + (((size_t)e * 8 + ct) * 32 + kb_off) * 8192);

  f32x4 acc[4][4];
  #pragma unroll
  for (int i = 0; i < 4; i++)
    #pragma unroll
    for (int j = 0; j < 4; j++) acc[i][j] = (f32x4){0.f, 0.f, 0.f, 0.f};

  auto stage = [&](int buf, int kb) {            // 8 vector-mem instrs / thread
    const char* ga = gA + (size_t)kb * 16384 + wave * 1024 + lane * 16;
    const char* gb = gB + (size_t)kb * 16384 + wave * 1024 + lane * 16;
    #pragma unroll
    for (int i = 0; i < 4; i++) {
      gld_lds16(ga + i * 4096, (char*)As[buf] + i * 4096 + wave * 1024);
      gld_lds16(gb + i * 4096, (char*)Bs[buf] + i * 4096 + wave * 1024);
    }
  };

  stage(0, 0);
  __syncthreads();
  for (int kb = 0; kb < NKBC; kb++) {
    int cur = kb & 1;
    if (kb + 1 < NKBC) {
      stage(cur ^ 1, kb + 1);
      asm volatile("s_waitcnt vmcnt(8)" ::: "memory");
    } else {
      asm volatile("s_waitcnt vmcnt(0)" ::: "memory");
    }
    __builtin_amdgcn_s_barrier();
    __builtin_amdgcn_sched_barrier(0);
    const char* Ab = (const char*)As[cur];
    const char* Bb = (const char*)Bs[cur];
    #pragma unroll
    for (int ks = 0; ks < 2; ks++) {
      s16x8 a[4], b[4];
      #pragma unroll
      for (int f = 0; f < 4; f++) {
        a[f] = *(const s16x8*)(Ab + tile_byte(wr * 64 + f * 16 + llo, ks * 64 + lhi * 16));
        b[f] = *(const s16x8*)(Bb + tile_byte(wc * 64 + f * 16 + llo, ks * 64 + lhi * 16));
      }
      #pragma unroll
      for (int fr = 0; fr < 4; fr++)
        #pragma unroll
        for (int fc = 0; fc < 4; fc++)
          acc[fr][fc] = __builtin_amdgcn_mfma_f32_16x16x32_bf16(a[fr], b[fc], acc[fr][fc], 0, 0, 0);
    }
    __builtin_amdgcn_sched_barrier(0);
    __builtin_amdgcn_s_barrier();
  }

  const float* b2e = b2 + e * DIM + ct * 128;
  #pragma unroll
  for (int fr = 0; fr < 4; fr++) {
    #pragma unroll
    for (int j = 0; j < 4; j++) {
      int q = rt * 128 + wr * 64 + fr * 16 + lhi * 4 + j;
      if (q < segcnt) {
        int slot = seg ? (TOK - 1 - q) : q;
        int t = tok_list[e * TOK + slot];
        float w = w_list[e * TOK + slot];
        float bs = add_b2 ? w : 0.f;
        #pragma unroll
        for (int fc = 0; fc < 4; fc++) {
          int col = wc * 64 + fc * 16 + llo;
          float val = w * acc[fr][fc][j] + bs * b2e[col];
          size_t idx = (size_t)t * DIM + ct * 128 + col;
          if (accum) y[idx] += val;
          else       y[idx] = val;
        }
      }
    }
  }
}

// ======================= legacy fallback (round-1 style) ====================
__global__ void transpose_cvt(const float* __restrict__ src, unsigned short* __restrict__ dst,
                              int R, int C) {
  __shared__ float tile[32][33];
  int e = blockIdx.z;
  const float* s = src + (size_t)e * R * C;
  unsigned short* d = dst + (size_t)e * R * C;
  int c0 = blockIdx.x * 32, r0 = blockIdx.y * 32;
  int tx = threadIdx.x, ty = threadIdx.y;
  #pragma unroll
  for (int i = 0; i < 32; i += 8)
    tile[ty + i][tx] = s[(size_t)(r0 + ty + i) * C + c0 + tx];
  __syncthreads();
  #pragma unroll
  for (int i = 0; i < 32; i += 8)
    d[(size_t)(c0 + ty + i) * R + r0 + tx] = f2bf(tile[tx][ty + i]);
}

__global__ void router_kernel(const float* __restrict__ x, const float* __restrict__ Wg,
                              int* __restrict__ counts, int* __restrict__ tok_list,
                              float* __restrict__ w_list) {
  int wave = threadIdx.x >> 6, lane = threadIdx.x & 63;
  int t = blockIdx.x * 4 + wave;
  const float* xr = x + (size_t)t * DIM;
  float acc[NEXP];
  #pragma unroll
  for (int e = 0; e < NEXP; e++) acc[e] = 0.f;
  for (int i = 0; i < DIM / 64; i++) {
    int dd = i * 64 + lane;
    float xv = xr[dd];
    const float* wr = Wg + (size_t)dd * NEXP;
    #pragma unroll
    for (int e = 0; e < NEXP; e++) acc[e] = fmaf(xv, wr[e], acc[e]);
  }
  #pragma unroll
  for (int e = 0; e < NEXP; e++) {
    float v = acc[e];
    #pragma unroll
    for (int off = 32; off >= 1; off >>= 1) v += __shfl_xor(v, off);
    acc[e] = v;
  }
  if (lane == 0) {
    float m = acc[0];
    #pragma unroll
    for (int e = 1; e < NEXP; e++) m = fmaxf(m, acc[e]);
    float p[NEXP], s = 0.f;
    #pragma unroll
    for (int e = 0; e < NEXP; e++) { p[e] = expf(acc[e] - m); s += p[e]; }
    float inv = 1.f / s;
    int i0 = 0; float v0 = p[0];
    #pragma unroll
    for (int e = 1; e < NEXP; e++) if (p[e] > v0) { v0 = p[e]; i0 = e; }
    int i1 = -1; float v1 = -1.f;
    #pragma unroll
    for (int e = 0; e < NEXP; e++) if (e != i0 && p[e] > v1) { v1 = p[e]; i1 = e; }
    v0 *= inv; v1 *= inv;
    float den = v0 + v1 + 1e-9f;
    float w0 = v0 / den, w1 = v1 / den;
    int q0 = atomicAdd(&counts[i0], 1);
    tok_list[i0 * TOK + q0] = t;           w_list[i0 * TOK + q0] = w0;
    int q1 = atomicAdd(&counts[8 + i1], 1);
    int p1 = TOK - 1 - q1;
    tok_list[i1 * TOK + p1] = t;           w_list[i1 * TOK + p1] = w1;
  }
}

__global__ __launch_bounds__(512, 4)
void moe_ffn_kernel(const float* __restrict__ x,
                    const unsigned short* __restrict__ w1t,
                    const unsigned short* __restrict__ w2t,
                    const float* __restrict__ b1, const float* __restrict__ b2,
                    const int* __restrict__ counts, const int* __restrict__ tok_list,
                    const float* __restrict__ w_list, float* __restrict__ y) {
  int zz = blockIdx.y, e = zz & 7, seg = zz >> 3;
  int segcnt = counts[seg * 8 + e];
  int row0 = blockIdx.x * 32;
  if (row0 >= segcnt) return;
  __shared__ unsigned short Xs[32 * DIM];
  __shared__ unsigned short hsl[32 * 64];
  __shared__ int tokS[32];
  __shared__ float wS[32];
  int tid = threadIdx.x, wave = tid >> 6, lane = tid & 63;
  if (tid < 32) {
    int q = row0 + tid;
    if (q < segcnt) {
      int slot = seg ? (TOK - 1 - q) : q;
      tokS[tid] = tok_list[e * TOK + slot]; wS[tid] = w_list[e * TOK + slot];
    } else { tokS[tid] = -1; wS[tid] = 0.f; }
  }
  __syncthreads();
  #pragma unroll
  for (int it = 0; it < 8; it++) {
    int chunk = it * 512 + tid;
    int r = chunk >> 7, c = (chunk & 127) * 8;
    int tok = tokS[r];
    float4 f0 = make_float4(0.f, 0.f, 0.f, 0.f), f1 = f0;
    if (tok >= 0) {
      const float4* xp = (const float4*)(x + (size_t)tok * DIM + c);
      f0 = xp[0]; f1 = xp[1];
    }
    s16x8 bv;
    bv[0] = (short)f2bf(f0.x); bv[1] = (short)f2bf(f0.y);
    bv[2] = (short)f2bf(f0.z); bv[3] = (short)f2bf(f0.w);
    bv[4] = (short)f2bf(f1.x); bv[5] = (short)f2bf(f1.y);
    bv[6] = (short)f2bf(f1.z); bv[7] = (short)f2bf(f1.w);
    int byte = (r * DIM + c) * 2; byte ^= (r & 7) << 4;
    *(s16x8*)((char*)Xs + byte) = bv;
  }
  __syncthreads();
  int rw = wave >> 2, cw = wave & 3;
  int lhi = lane >> 4, llo = lane & 15;
  f32x4 acc[16];
  #pragma unroll
  for (int i = 0; i < 16; i++) acc[i] = (f32x4){0.f, 0.f, 0.f, 0.f};
  int arow = rw * 16 + llo;
  int abase = arow * (DIM * 2) + lhi * 16;
  int aswz = (arow & 7) << 4;
  int h_abase = arow * (64 * 2) + lhi * 16;
  const size_t eHD = (size_t)e * HID * DIM;
  const unsigned short* w2e = w2t + (size_t)e * DIM * HID;
  for (int hc = 0; hc < HID; hc += 64) {
    f32x4 c1 = (f32x4){0.f, 0.f, 0.f, 0.f};
    const unsigned short* w1p = w1t + eHD + (size_t)(hc + cw * 16 + llo) * DIM + lhi * 8;
    #pragma unroll 4
    for (int k = 0; k < DIM; k += 32) {
      s16x8 a = *(const s16x8*)((const char*)Xs + ((abase + k * 2) ^ aswz));
      s16x8 b = *(const s16x8*)(w1p + k);
      c1 = __builtin_amdgcn_mfma_f32_16x16x32_bf16(a, b, c1, 0, 0, 0);
    }
    float b1v = b1[e * HID + hc + cw * 16 + llo];
    __syncthreads();
    #pragma unroll
    for (int j = 0; j < 4; j++) {
      int r = rw * 16 + lhi * 4 + j;
      float v = fmaxf(c1[j] + b1v, 0.f);
      int byte = (r * 64 + cw * 16 + llo) * 2; byte ^= (r & 7) << 4;
      *(unsigned short*)((char*)hsl + byte) = f2bf(v);
    }
    __syncthreads();
    s16x8 a0 = *(const s16x8*)((const char*)hsl + ((h_abase + 0)  ^ aswz));
    s16x8 a1 = *(const s16x8*)((const char*)hsl + ((h_abase + 64) ^ aswz));
    const unsigned short* w2p0 = w2e + hc + lhi * 8;
    #pragma unroll 4
    for (int ctile = 0; ctile < 16; ctile++) {
      int dcol = cw * 256 + ctile * 16 + llo;
      const unsigned short* bp = w2p0 + (size_t)dcol * HID;
      s16x8 b0 = *(const s16x8*)(bp);
      s16x8 b1f = *(const s16x8*)(bp + 32);
      acc[ctile] = __builtin_amdgcn_mfma_f32_16x16x32_bf16(a0, b0, acc[ctile], 0, 0, 0);
      acc[ctile] = __builtin_amdgcn_mfma_f32_16x16x32_bf16(a1, b1f, acc[ctile], 0, 0, 0);
    }
  }
  const float* b2e = b2 + e * DIM;
  #pragma unroll
  for (int ctile = 0; ctile < 16; ctile++) {
    int dcol = cw * 256 + ctile * 16 + llo;
    float b2v = b2e[dcol];
    #pragma unroll
    for (int j = 0; j < 4; j++) {
      int r = rw * 16 + lhi * 4 + j;
      int tok = tokS[r];
      if (tok >= 0) atomicAdd(&y[(size_t)tok * DIM + dcol], wS[r] * (acc[ctile][j] + b2v));
    }
  }
}

// ===========================================================================
extern "C" void kernel_launch(void* const* d_in, const int* in_sizes, int n_in,
                              void* d_out, int out_size, void* d_ws, size_t ws_size,
                              hipStream_t stream) {
  const float* x  = (const float*)d_in[0];
  const float* Wg = (const float*)d_in[1];
  const float* W1 = (const float*)d_in[2];
  const float* b1 = (const float*)d_in[3];
  const float* W2 = (const float*)d_in[4];
  const float* b2 = (const float*)d_in[5];
  float* y = (float*)d_out;
  char* ws = (char*)d_ws;

  const size_t O_COUNTS = 0;
  const size_t O_OFF    = 1024;
  const size_t O_TOK    = 2048;
  const size_t O_W      = O_TOK + (size_t)NEXP * TOK * 4;            // 526336
  const size_t O_WGT    = O_W + (size_t)NEXP * TOK * 4;              // 1050624
  const size_t O_SEL    = O_WGT + (size_t)NEXP * DIM * 4;            // +32KB
  const size_t O_WP     = O_SEL + (size_t)TOK * 4;                   // +64KB
  const size_t O_W1S    = O_WP + (size_t)TOK * 8;                    // +128KB
  const size_t O_W2S    = O_W1S + (size_t)NEXP * 16 * 16 * 8192 * 2;    // +33.55MB
  const size_t O_XBF    = O_W2S + (size_t)NEXP * 8 * 32 * 8192 * 2;     // +33.55MB
  const size_t O_HS     = O_XBF + (size_t)TOK * DIM * 2;                // +33.55MB (~102MB)

  // largest H-chunk whose hs fits: hs = 34816 padded rows * Hc * 2 B
  int Hc = 0;
  if (ws_size > O_HS) {
    size_t avail = ws_size - O_HS;
    for (int hc = HID; hc >= 128; hc >>= 1)
      if ((size_t)34816 * hc * 2 <= avail) { Hc = hc; break; }
  }

  if (Hc) {
    int*   counts   = (int*)(ws + O_COUNTS);
    int*   offp     = (int*)(ws + O_OFF);
    int*   tok_list = (int*)(ws + O_TOK);
    float* w_list   = (float*)(ws + O_W);
    float* WgT      = (float*)(ws + O_WGT);
    int*   sel      = (int*)(ws + O_SEL);
    float2* wp      = (float2*)(ws + O_WP);
    unsigned short* w1s = (unsigned short*)(ws + O_W1S);
    unsigned short* w2s = (unsigned short*)(ws + O_W2S);
    unsigned short* xbf = (unsigned short*)(ws + O_XBF);
    unsigned short* hs  = (unsigned short*)(ws + O_HS);

    hipMemsetAsync(counts, 0, 2048, stream);
    wg_tr<<<32, 256, 0, stream>>>(Wg, WgT);
    prep_tiles<<<dim3(HID / 128, DIM / 64, NEXP), 256, 0, stream>>>(W1, w1s, DIM, HID);
    prep_tiles<<<dim3(DIM / 128, HID / 64, NEXP), 256, 0, stream>>>(W2, w2s, HID, DIM);
    router_logits_cvt<<<TOK / 4, 256, 0, stream>>>(x, WgT, xbf, sel, wp);
    router_scatter<<<TOK / 256, 256, 0, stream>>>(sel, wp, counts, tok_list, w_list);
    calc_off<<<1, 64, 0, stream>>>(counts, offp);

    int nch = HID / Hc, nkbc = Hc / 64, nct = Hc / 128;
    for (int ch = 0; ch < nch; ch++) {
      moe_gemm1<<<272 * nct, 256, 0, stream>>>(
          xbf, w1s, b1, counts, offp, tok_list, hs, ch * nct, nkbc, nct);
      for (int seg = 0; seg < 2; seg++) {
        int add_b2 = (ch == 0) ? 1 : 0;
        int accum  = (ch == 0 && seg == 0) ? 0 : 1;
        int kb_off = ch * nkbc;
        #define LG2(NK) moe_gemm2<NK><<<136 * 8, 256, 0, stream>>>( \
            hs, w2s, b2, counts, offp, tok_list, w_list, y, seg, kb_off, add_b2, accum)
        switch (nkbc) {
          case 32: LG2(32); break;
          case 16: LG2(16); break;
          case 8:  LG2(8);  break;
          case 4:  LG2(4);  break;
          default: LG2(2);  break;
        }
        #undef LG2
      }
    }
  } else {
    // legacy path (ws too small)
    int*   counts   = (int*)ws;
    int*   tok_list = (int*)(ws + 2048);
    float* w_list   = (float*)(ws + 2048 + (size_t)NEXP * TOK * 4);
    unsigned short* w1t = (unsigned short*)(ws + 2048 + (size_t)NEXP * TOK * 8);
    unsigned short* w2t = w1t + (size_t)NEXP * HID * DIM;

    hipMemsetAsync(d_out, 0, (size_t)out_size * sizeof(float), stream);
    hipMemsetAsync(counts, 0, 2048, stream);
    transpose_cvt<<<dim3(HID / 32, DIM / 32, NEXP), dim3(32, 8), 0, stream>>>(W1, w1t, DIM, HID);
    transpose_cvt<<<dim3(DIM / 32, HID / 32, NEXP), dim3(32, 8), 0, stream>>>(W2, w2t, HID, DIM);
    router_kernel<<<TOK / 4, 256, 0, stream>>>(x, Wg, counts, tok_list, w_list);
    moe_ffn_kernel<<<dim3(TOK / 32, 16), 512, 0, stream>>>(
        x, w1t, w2t, b1, b2, counts, tok_list, w_list, y);
  }
}

// Round 10
// 604.416 us; speedup vs baseline: 1.0504x; 1.0504x over previous
//
#include <hip/hip_runtime.h>
#include <hip/hip_bf16.h>

#define TOK 16384
#define DIM 1024
#define HID 2048
#define NEXP 8

typedef __attribute__((ext_vector_type(4))) float f32x4;
typedef __attribute__((ext_vector_type(8))) short s16x8;

__device__ __forceinline__ unsigned short f2bf(float f) {
  union { float f; unsigned u; } v; v.f = f;
  unsigned r = v.u + 0x7fffu + ((v.u >> 16) & 1u);   // RNE
  return (unsigned short)(r >> 16);
}
// byte offset of element (r, byte-col kk2) inside a [128 rows][128 B] tile, XOR-swizzled
__device__ __forceinline__ int tile_byte(int r, int kk2) {
  return (r * 128 + kk2) ^ ((r & 7) << 4);
}
__device__ __forceinline__ void gld_lds16(const void* g, void* l) {
  __builtin_amdgcn_global_load_lds(
      (const __attribute__((address_space(1))) unsigned int*)g,
      (__attribute__((address_space(3))) unsigned int*)l, 16, 0, 0);
}
// bijective XCD-chunked block remap (m204): physical p (xcd = p%8) -> logical
__device__ __forceinline__ int xcd_swz(int p, int nwg) {
  int q = nwg >> 3, r = nwg & 7;
  int xcd = p & 7, idx = p >> 3;
  return (xcd < r ? xcd * (q + 1) : r * (q + 1) + (xcd - r) * q) + idx;
}

// Wg [D][E] -> WgT [E][D] fp32 (tiny, 32 KB)
__global__ void wg_tr(const float* __restrict__ Wg, float* __restrict__ WgT) {
  int i = blockIdx.x * 256 + threadIdx.x;   // 8192
  int e = i >> 10, dd = i & 1023;
  WgT[i] = Wg[dd * NEXP + e];
}

// ---------------------------------------------------------------------------
// Weight prepass: fp32 src [E][rows][cols] -> bf16 128-wide tiled-swizzled
// dst[e][ct][kb][16KB tile]; tile(r<128, kk<64) = src[e][kb*64+kk][ct*128+r]
// ---------------------------------------------------------------------------
__global__ void prep_tiles(const float* __restrict__ src, unsigned short* __restrict__ dst,
                           int rows, int cols) {
  int ct = blockIdx.x, kb = blockIdx.y, e = blockIdx.z;
  int nct = gridDim.x, nkb = gridDim.y;
  __shared__ __align__(16) unsigned short tile[8192];
  const float* s = src + ((size_t)e * rows + kb * 64) * cols + ct * 128;
  int tid = threadIdx.x;  // 256
  #pragma unroll
  for (int it = 0; it < 8; it++) {
    int idx = it * 256 + tid;          // 2048 float4 chunks
    int kk = idx >> 5;                 // 0..63
    int r4 = (idx & 31) * 4;           // 0..124
    float4 v = *(const float4*)(s + (size_t)kk * cols + r4);
    char* tb = (char*)tile;
    *(unsigned short*)(tb + tile_byte(r4 + 0, kk * 2)) = f2bf(v.x);
    *(unsigned short*)(tb + tile_byte(r4 + 1, kk * 2)) = f2bf(v.y);
    *(unsigned short*)(tb + tile_byte(r4 + 2, kk * 2)) = f2bf(v.z);
    *(unsigned short*)(tb + tile_byte(r4 + 3, kk * 2)) = f2bf(v.w);
  }
  __syncthreads();
  unsigned short* d = dst + (((size_t)e * nct + ct) * nkb + kb) * 8192;
  #pragma unroll
  for (int it = 0; it < 4; it++) {
    int o = it * 256 + tid;
    *(s16x8*)(d + o * 8) = *(const s16x8*)((const char*)tile + o * 16);
  }
}

// ---------------------------------------------------------------------------
// Router phase A (fused x->bf16 convert): fp32 logits via coalesced WgT,
// exact top-2, no atomics.
// ---------------------------------------------------------------------------
__global__ __launch_bounds__(256)
void router_logits_cvt(const float* __restrict__ x, const float* __restrict__ WgT,
                       unsigned short* __restrict__ xbf,
                       int* __restrict__ sel, float2* __restrict__ wp) {
  int wave = threadIdx.x >> 6, lane = threadIdx.x & 63;
  int t = blockIdx.x * 4 + wave;
  const f32x4* xr = (const f32x4*)(x + (size_t)t * DIM);
  unsigned short* xb = xbf + (size_t)t * DIM;
  float acc[NEXP];
  #pragma unroll
  for (int e = 0; e < NEXP; e++) acc[e] = 0.f;
  #pragma unroll
  for (int q = 0; q < 4; q++) {
    f32x4 xv = xr[q * 64 + lane];
    ushort4 bv;
    bv.x = f2bf(xv[0]); bv.y = f2bf(xv[1]); bv.z = f2bf(xv[2]); bv.w = f2bf(xv[3]);
    *(ushort4*)(xb + (q * 64 + lane) * 4) = bv;
    #pragma unroll
    for (int e = 0; e < NEXP; e++) {
      f32x4 wv = *(const f32x4*)(WgT + (size_t)e * DIM + (q * 64 + lane) * 4);
      acc[e] = fmaf(xv[3], wv[3], fmaf(xv[2], wv[2], fmaf(xv[1], wv[1], fmaf(xv[0], wv[0], acc[e]))));
    }
  }
  #pragma unroll
  for (int e = 0; e < NEXP; e++) {
    float v = acc[e];
    #pragma unroll
    for (int off = 32; off >= 1; off >>= 1) v += __shfl_xor(v, off);
    acc[e] = v;
  }
  if (lane == 0) {
    float m = acc[0];
    #pragma unroll
    for (int e = 1; e < NEXP; e++) m = fmaxf(m, acc[e]);
    float p[NEXP], s = 0.f;
    #pragma unroll
    for (int e = 0; e < NEXP; e++) { p[e] = expf(acc[e] - m); s += p[e]; }
    float inv = 1.f / s;
    int i0 = 0; float v0 = p[0];
    #pragma unroll
    for (int e = 1; e < NEXP; e++) if (p[e] > v0) { v0 = p[e]; i0 = e; }   // strict > = low-index tie-break
    int i1 = -1; float v1 = -1.f;
    #pragma unroll
    for (int e = 0; e < NEXP; e++) if (e != i0 && p[e] > v1) { v1 = p[e]; i1 = e; }
    v0 *= inv; v1 *= inv;
    float den = v0 + v1 + 1e-9f;
    sel[t] = i0 | (i1 << 4);
    wp[t] = make_float2(v0 / den, v1 / den);
  }
}

// ---------------------------------------------------------------------------
// Router phase B: ballot-ranked scatter; 1 atomic per (block,bin).
// ---------------------------------------------------------------------------
__global__ __launch_bounds__(256)
void router_scatter(const int* __restrict__ sel, const float2* __restrict__ wp,
                    int* __restrict__ counts, int* __restrict__ tok_list,
                    float* __restrict__ w_list) {
  __shared__ int lh0[4][16], lh1[4][16];
  __shared__ int bbase[16];
  int tid = threadIdx.x, wave = tid >> 6, lane = tid & 63;
  int t = blockIdx.x * 256 + tid;
  int s = sel[t];
  int b0 = s & 15;
  int b1 = 8 + ((s >> 4) & 15);
  float2 w = wp[t];
  unsigned long long lt = (lane == 63) ? ~0ull >> 1 : (((unsigned long long)1 << lane) - 1);
  int r0 = 0, r1 = 0;
  #pragma unroll
  for (int b = 0; b < 8; b++) {
    unsigned long long m0 = __ballot(b0 == b);
    if (b0 == b) r0 = __popcll(m0 & lt);
    if (lane == 0) { lh0[wave][b] = __popcll(m0); lh1[wave][b] = 0; }
  }
  #pragma unroll
  for (int b = 8; b < 16; b++) {
    unsigned long long m1 = __ballot(b1 == b);
    if (b1 == b) r1 = __popcll(m1 & lt);
    if (lane == 0) { lh1[wave][b] = __popcll(m1); lh0[wave][b] = 0; }
  }
  __syncthreads();
  if (tid < 16) {
    int h = 0;
    #pragma unroll
    for (int v = 0; v < 4; v++) h += lh0[v][tid] + lh1[v][tid];
    bbase[tid] = atomicAdd(&counts[tid], h);
  }
  __syncthreads();
  int p0 = bbase[b0] + r0;
  int p1 = bbase[b1] + r1;
  #pragma unroll
  for (int v = 0; v < 4; v++) {
    if (v < wave) { p0 += lh0[v][b0]; p1 += lh1[v][b1]; }
  }
  int e0 = b0, e1 = b1 - 8;
  tok_list[e0 * TOK + p0] = t;
  w_list[e0 * TOK + p0] = w.x;
  int q1 = TOK - 1 - p1;
  tok_list[e1 * TOK + q1] = t;
  w_list[e1 * TOK + q1] = w.y;
}

// off[e*2+seg] = prefix of 128-padded segment row counts
__global__ void calc_off(const int* __restrict__ counts, int* __restrict__ off) {
  if (threadIdx.x == 0 && blockIdx.x == 0) {
    int a = 0;
    for (int e = 0; e < NEXP; e++)
      for (int s = 0; s < 2; s++) {
        off[e * 2 + s] = a;
        a += (counts[s * 8 + e] + 127) & ~127;
      }
  }
}

// ---------------------------------------------------------------------------
// GEMM1 (r7 / best config, unchanged): 128x128 tile, BK=64, 4 waves (2x2),
// single-buffer 32KB LDS, 2 barriers/K-step. 1D grid, ct-fastest + XCD swizzle.
// ---------------------------------------------------------------------------
__global__ __launch_bounds__(256, 4)
void moe_gemm1(const unsigned short* __restrict__ xbf, const unsigned short* __restrict__ w1s,
               const float* __restrict__ b1, const int* __restrict__ counts,
               const int* __restrict__ off, const int* __restrict__ tok_list,
               unsigned short* __restrict__ h_s, int ct_off, int nkbc, int nct) {
  int logical = xcd_swz(blockIdx.x, gridDim.x);
  int ct_l = logical % nct;
  int g = logical / nct;
  int e = -1, seg = 0, rt = 0, segcnt = 0, base = 0;
  #pragma unroll
  for (int zz = 0; zz < 16; zz++) {
    int ee = zz >> 1, ss = zz & 1;
    int c = counts[ss * 8 + ee];
    int nt = (c + 127) >> 7;
    if (e < 0 && g < base + nt) { e = ee; seg = ss; rt = g - base; segcnt = c; }
    base += nt;
  }
  if (e < 0) return;

  __shared__ __align__(16) unsigned short As[8192];
  __shared__ __align__(16) unsigned short Bs[8192];
  __shared__ int tokS[128];

  int tid = threadIdx.x, wave = tid >> 6, lane = tid & 63;
  int llo = lane & 15, lhi = lane >> 4;
  int wr = wave >> 1, wc = wave & 1;
  int ct_g = ct_off + ct_l;

  if (tid < 128) {
    int q = rt * 128 + tid;
    int qq = q < segcnt ? q : segcnt - 1;       // clamp: dup rows land in hs pad, discarded later
    int slot = seg ? (TOK - 1 - qq) : qq;
    tokS[tid] = tok_list[e * TOK + slot];
  }
  __syncthreads();

  // A sources: linear LDS chunk (i*256+tid) covers (row = i*32 + tid/8, c16 = tid&7);
  // source chunk pre-swizzled so swizzled ds_read gets original bytes (rule #21).
  const char* srcA[4];
  #pragma unroll
  for (int i = 0; i < 4; i++) {
    int r = i * 32 + (tid >> 3);
    srcA[i] = (const char*)xbf + (size_t)tokS[r] * (DIM * 2) + (((tid & 7) ^ (r & 7)) * 16);
  }
  const char* gB = (const char*)(w1s + (((size_t)e * 16 + ct_g) * 16) * 8192);

  f32x4 acc[4][4];
  #pragma unroll
  for (int i = 0; i < 4; i++)
    #pragma unroll
    for (int j = 0; j < 4; j++) acc[i][j] = (f32x4){0.f, 0.f, 0.f, 0.f};

  for (int kb = 0; kb < 16; kb++) {
    #pragma unroll
    for (int i = 0; i < 4; i++)
      gld_lds16(srcA[i] + kb * 128, (char*)As + i * 4096 + wave * 1024);
    const char* gs = gB + (size_t)kb * 16384 + wave * 1024 + lane * 16;
    #pragma unroll
    for (int i = 0; i < 4; i++)
      gld_lds16(gs + i * 4096, (char*)Bs + i * 4096 + wave * 1024);
    __syncthreads();
    #pragma unroll
    for (int ks = 0; ks < 2; ks++) {
      s16x8 a[4], b[4];
      #pragma unroll
      for (int f = 0; f < 4; f++) {
        a[f] = *(const s16x8*)((const char*)As + tile_byte(wr * 64 + f * 16 + llo, ks * 64 + lhi * 16));
        b[f] = *(const s16x8*)((const char*)Bs + tile_byte(wc * 64 + f * 16 + llo, ks * 64 + lhi * 16));
      }
      #pragma unroll
      for (int fr = 0; fr < 4; fr++)
        #pragma unroll
        for (int fc = 0; fc < 4; fc++)
          acc[fr][fc] = __builtin_amdgcn_mfma_f32_16x16x32_bf16(a[fr], b[fc], acc[fr][fc], 0, 0, 0);
    }
    __syncthreads();
  }

  // epilogue: relu(acc + b1) -> hs 128-tiled-swizzled bf16 (chunk-local tiles)
  size_t grt = (size_t)(off[e * 2 + seg] >> 7) + rt;
  unsigned short* hb = h_s + grt * ((size_t)nkbc * 8192);
  const float* b1e = b1 + e * HID + ct_g * 128;
  #pragma unroll
  for (int fc = 0; fc < 4; fc++) {
    int col = wc * 64 + fc * 16 + llo;        // 0..127 within ct
    float bv = b1e[col];
    char* tb = (char*)(hb + ((size_t)(ct_l * 2 + (col >> 6))) * 8192);
    int kk2 = (col & 63) * 2;
    #pragma unroll
    for (int fr = 0; fr < 4; fr++) {
      int r0 = wr * 64 + fr * 16 + lhi * 4;
      #pragma unroll
      for (int j = 0; j < 4; j++) {
        float v = fmaxf(acc[fr][fc][j] + bv, 0.f);
        *(unsigned short*)(tb + tile_byte(r0 + j, kk2)) = f2bf(v);
      }
    }
  }
}

// ---------------------------------------------------------------------------
// GEMM2 (WIDENED, per seg/chunk): 128x256 tile — one A-stage feeds two B-tiles
// (2x MFMA per staged byte, half the A streams). Single-buffer 48KB LDS,
// 2 barriers/K-step (r7 semantics). ct2-fastest + XCD chunk swizzle.
// ---------------------------------------------------------------------------
template<int NKBC>
__global__ __launch_bounds__(256, 2)
void moe_gemm2(const unsigned short* __restrict__ h_s, const unsigned short* __restrict__ w2s,
               const float* __restrict__ b2, const int* __restrict__ counts,
               const int* __restrict__ off, const int* __restrict__ tok_list,
               const float* __restrict__ w_list, float* __restrict__ y,
               int seg, int kb_off, int add_b2, int accum) {
  int logical = xcd_swz(blockIdx.x, gridDim.x);
  int ct2 = logical & 3;       // DIM/256 = 4 column-pair tiles, fastest
  int g = logical >> 2;
  int e = -1, rt = 0, segcnt = 0, base = 0;
  #pragma unroll
  for (int ee = 0; ee < 8; ee++) {
    int c = counts[seg * 8 + ee];
    int nt = (c + 127) >> 7;
    if (e < 0 && g < base + nt) { e = ee; rt = g - base; segcnt = c; }
    base += nt;
  }
  if (e < 0) return;

  __shared__ __align__(16) unsigned short As[8192];      // A [128 x 64]
  __shared__ __align__(16) unsigned short Bs[16384];     // B [2 ct-tiles][128 x 64]

  int tid = threadIdx.x, wave = tid >> 6, lane = tid & 63;
  int llo = lane & 15, lhi = lane >> 4;
  int wr = wave >> 1, wc = wave & 1;

  size_t grt = (size_t)(off[e * 2 + seg] >> 7) + rt;
  const char* gA = (const char*)(h_s + grt * ((size_t)NKBC * 8192));
  const char* gB0 = (const char*)(w2s + (((size_t)e * 8 + ct2 * 2) * 32 + kb_off) * 8192);
  const char* gB1 = gB0 + (size_t)32 * 16384;   // next ct tile (stride = nkb*16KB)

  f32x4 acc[4][8];
  #pragma unroll
  for (int i = 0; i < 4; i++)
    #pragma unroll
    for (int j = 0; j < 8; j++) acc[i][j] = (f32x4){0.f, 0.f, 0.f, 0.f};

  for (int kb = 0; kb < NKBC; kb++) {
    const char* ga  = gA  + (size_t)kb * 16384 + wave * 1024 + lane * 16;
    const char* gb0 = gB0 + (size_t)kb * 16384 + wave * 1024 + lane * 16;
    const char* gb1 = gB1 + (size_t)kb * 16384 + wave * 1024 + lane * 16;
    #pragma unroll
    for (int i = 0; i < 4; i++) {
      gld_lds16(ga  + i * 4096, (char*)As + i * 4096 + wave * 1024);
      gld_lds16(gb0 + i * 4096, (char*)Bs + i * 4096 + wave * 1024);
      gld_lds16(gb1 + i * 4096, (char*)Bs + 16384 + i * 4096 + wave * 1024);
    }
    __syncthreads();
    #pragma unroll
    for (int ks = 0; ks < 2; ks++) {
      s16x8 a[4], b[8];
      #pragma unroll
      for (int f = 0; f < 4; f++)
        a[f] = *(const s16x8*)((const char*)As + tile_byte(wr * 64 + f * 16 + llo, ks * 64 + lhi * 16));
      #pragma unroll
      for (int f = 0; f < 8; f++)
        b[f] = *(const s16x8*)((const char*)Bs + wc * 16384 + tile_byte(f * 16 + llo, ks * 64 + lhi * 16));
      #pragma unroll
      for (int fr = 0; fr < 4; fr++)
        #pragma unroll
        for (int fc = 0; fc < 8; fc++)
          acc[fr][fc] = __builtin_amdgcn_mfma_f32_16x16x32_bf16(a[fr], b[fc], acc[fr][fc], 0, 0, 0);
    }
    __syncthreads();
  }

  const float* b2e = b2 + e * DIM + ct2 * 256;
  #pragma unroll
  for (int fr = 0; fr < 4; fr++) {
    #pragma unroll
    for (int j = 0; j < 4; j++) {
      int q = rt * 128 + wr * 64 + fr * 16 + lhi * 4 + j;
      if (q < segcnt) {
        int slot = seg ? (TOK - 1 - q) : q;
        int t = tok_list[e * TOK + slot];
        float w = w_list[e * TOK + slot];
        float bs = add_b2 ? w : 0.f;
        #pragma unroll
        for (int fc = 0; fc < 8; fc++) {
          int col = wc * 128 + fc * 16 + llo;   // 0..255 within ct2 pair
          float val = w * acc[fr][fc][j] + bs * b2e[col];
          size_t idx = (size_t)t * DIM + ct2 * 256 + col;
          if (accum) y[idx] += val;
          else       y[idx] = val;
        }
      }
    }
  }
}

// ======================= legacy fallback (round-1 style) ====================
__global__ void transpose_cvt(const float* __restrict__ src, unsigned short* __restrict__ dst,
                              int R, int C) {
  __shared__ float tile[32][33];
  int e = blockIdx.z;
  const float* s = src + (size_t)e * R * C;
  unsigned short* d = dst + (size_t)e * R * C;
  int c0 = blockIdx.x * 32, r0 = blockIdx.y * 32;
  int tx = threadIdx.x, ty = threadIdx.y;
  #pragma unroll
  for (int i = 0; i < 32; i += 8)
    tile[ty + i][tx] = s[(size_t)(r0 + ty + i) * C + c0 + tx];
  __syncthreads();
  #pragma unroll
  for (int i = 0; i < 32; i += 8)
    d[(size_t)(c0 + ty + i) * R + r0 + tx] = f2bf(tile[tx][ty + i]);
}

__global__ void router_kernel(const float* __restrict__ x, const float* __restrict__ Wg,
                              int* __restrict__ counts, int* __restrict__ tok_list,
                              float* __restrict__ w_list) {
  int wave = threadIdx.x >> 6, lane = threadIdx.x & 63;
  int t = blockIdx.x * 4 + wave;
  const float* xr = x + (size_t)t * DIM;
  float acc[NEXP];
  #pragma unroll
  for (int e = 0; e < NEXP; e++) acc[e] = 0.f;
  for (int i = 0; i < DIM / 64; i++) {
    int dd = i * 64 + lane;
    float xv = xr[dd];
    const float* wr = Wg + (size_t)dd * NEXP;
    #pragma unroll
    for (int e = 0; e < NEXP; e++) acc[e] = fmaf(xv, wr[e], acc[e]);
  }
  #pragma unroll
  for (int e = 0; e < NEXP; e++) {
    float v = acc[e];
    #pragma unroll
    for (int off = 32; off >= 1; off >>= 1) v += __shfl_xor(v, off);
    acc[e] = v;
  }
  if (lane == 0) {
    float m = acc[0];
    #pragma unroll
    for (int e = 1; e < NEXP; e++) m = fmaxf(m, acc[e]);
    float p[NEXP], s = 0.f;
    #pragma unroll
    for (int e = 0; e < NEXP; e++) { p[e] = expf(acc[e] - m); s += p[e]; }
    float inv = 1.f / s;
    int i0 = 0; float v0 = p[0];
    #pragma unroll
    for (int e = 1; e < NEXP; e++) if (p[e] > v0) { v0 = p[e]; i0 = e; }
    int i1 = -1; float v1 = -1.f;
    #pragma unroll
    for (int e = 0; e < NEXP; e++) if (e != i0 && p[e] > v1) { v1 = p[e]; i1 = e; }
    v0 *= inv; v1 *= inv;
    float den = v0 + v1 + 1e-9f;
    float w0 = v0 / den, w1 = v1 / den;
    int q0 = atomicAdd(&counts[i0], 1);
    tok_list[i0 * TOK + q0] = t;           w_list[i0 * TOK + q0] = w0;
    int q1 = atomicAdd(&counts[8 + i1], 1);
    int p1 = TOK - 1 - q1;
    tok_list[i1 * TOK + p1] = t;           w_list[i1 * TOK + p1] = w1;
  }
}

__global__ __launch_bounds__(512, 4)
void moe_ffn_kernel(const float* __restrict__ x,
                    const unsigned short* __restrict__ w1t,
                    const unsigned short* __restrict__ w2t,
                    const float* __restrict__ b1, const float* __restrict__ b2,
                    const int* __restrict__ counts, const int* __restrict__ tok_list,
                    const float* __restrict__ w_list, float* __restrict__ y) {
  int zz = blockIdx.y, e = zz & 7, seg = zz >> 3;
  int segcnt = counts[seg * 8 + e];
  int row0 = blockIdx.x * 32;
  if (row0 >= segcnt) return;
  __shared__ unsigned short Xs[32 * DIM];
  __shared__ unsigned short hsl[32 * 64];
  __shared__ int tokS[32];
  __shared__ float wS[32];
  int tid = threadIdx.x, wave = tid >> 6, lane = tid & 63;
  if (tid < 32) {
    int q = row0 + tid;
    if (q < segcnt) {
      int slot = seg ? (TOK - 1 - q) : q;
      tokS[tid] = tok_list[e * TOK + slot]; wS[tid] = w_list[e * TOK + slot];
    } else { tokS[tid] = -1; wS[tid] = 0.f; }
  }
  __syncthreads();
  #pragma unroll
  for (int it = 0; it < 8; it++) {
    int chunk = it * 512 + tid;
    int r = chunk >> 7, c = (chunk & 127) * 8;
    int tok = tokS[r];
    float4 f0 = make_float4(0.f, 0.f, 0.f, 0.f), f1 = f0;
    if (tok >= 0) {
      const float4* xp = (const float4*)(x + (size_t)tok * DIM + c);
      f0 = xp[0]; f1 = xp[1];
    }
    s16x8 bv;
    bv[0] = (short)f2bf(f0.x); bv[1] = (short)f2bf(f0.y);
    bv[2] = (short)f2bf(f0.z); bv[3] = (short)f2bf(f0.w);
    bv[4] = (short)f2bf(f1.x); bv[5] = (short)f2bf(f1.y);
    bv[6] = (short)f2bf(f1.z); bv[7] = (short)f2bf(f1.w);
    int byte = (r * DIM + c) * 2; byte ^= (r & 7) << 4;
    *(s16x8*)((char*)Xs + byte) = bv;
  }
  __syncthreads();
  int rw = wave >> 2, cw = wave & 3;
  int lhi = lane >> 4, llo = lane & 15;
  f32x4 acc[16];
  #pragma unroll
  for (int i = 0; i < 16; i++) acc[i] = (f32x4){0.f, 0.f, 0.f, 0.f};
  int arow = rw * 16 + llo;
  int abase = arow * (DIM * 2) + lhi * 16;
  int aswz = (arow & 7) << 4;
  int h_abase = arow * (64 * 2) + lhi * 16;
  const size_t eHD = (size_t)e * HID * DIM;
  const unsigned short* w2e = w2t + (size_t)e * DIM * HID;
  for (int hc = 0; hc < HID; hc += 64) {
    f32x4 c1 = (f32x4){0.f, 0.f, 0.f, 0.f};
    const unsigned short* w1p = w1t + eHD + (size_t)(hc + cw * 16 + llo) * DIM + lhi * 8;
    #pragma unroll 4
    for (int k = 0; k < DIM; k += 32) {
      s16x8 a = *(const s16x8*)((const char*)Xs + ((abase + k * 2) ^ aswz));
      s16x8 b = *(const s16x8*)(w1p + k);
      c1 = __builtin_amdgcn_mfma_f32_16x16x32_bf16(a, b, c1, 0, 0, 0);
    }
    float b1v = b1[e * HID + hc + cw * 16 + llo];
    __syncthreads();
    #pragma unroll
    for (int j = 0; j < 4; j++) {
      int r = rw * 16 + lhi * 4 + j;
      float v = fmaxf(c1[j] + b1v, 0.f);
      int byte = (r * 64 + cw * 16 + llo) * 2; byte ^= (r & 7) << 4;
      *(unsigned short*)((char*)hsl + byte) = f2bf(v);
    }
    __syncthreads();
    s16x8 a0 = *(const s16x8*)((const char*)hsl + ((h_abase + 0)  ^ aswz));
    s16x8 a1 = *(const s16x8*)((const char*)hsl + ((h_abase + 64) ^ aswz));
    const unsigned short* w2p0 = w2e + hc + lhi * 8;
    #pragma unroll 4
    for (int ctile = 0; ctile < 16; ctile++) {
      int dcol = cw * 256 + ctile * 16 + llo;
      const unsigned short* bp = w2p0 + (size_t)dcol * HID;
      s16x8 b0 = *(const s16x8*)(bp);
      s16x8 b1f = *(const s16x8*)(bp + 32);
      acc[ctile] = __builtin_amdgcn_mfma_f32_16x16x32_bf16(a0, b0, acc[ctile], 0, 0, 0);
      acc[ctile] = __builtin_amdgcn_mfma_f32_16x16x32_bf16(a1, b1f, acc[ctile], 0, 0, 0);
    }
  }
  const float* b2e = b2 + e * DIM;
  #pragma unroll
  for (int ctile = 0; ctile < 16; ctile++) {
    int dcol = cw * 256 + ctile * 16 + llo;
    float b2v = b2e[dcol];
    #pragma unroll
    for (int j = 0; j < 4; j++) {
      int r = rw * 16 + lhi * 4 + j;
      int tok = tokS[r];
      if (tok >= 0) atomicAdd(&y[(size_t)tok * DIM + dcol], wS[r] * (acc[ctile][j] + b2v));
    }
  }
}

// ===========================================================================
extern "C" void kernel_launch(void* const* d_in, const int* in_sizes, int n_in,
                              void* d_out, int out_size, void* d_ws, size_t ws_size,
                              hipStream_t stream) {
  const float* x  = (const float*)d_in[0];
  const float* Wg = (const float*)d_in[1];
  const float* W1 = (const float*)d_in[2];
  const float* b1 = (const float*)d_in[3];
  const float* W2 = (const float*)d_in[4];
  const float* b2 = (const float*)d_in[5];
  float* y = (float*)d_out;
  char* ws = (char*)d_ws;

  const size_t O_COUNTS = 0;
  const size_t O_OFF    = 1024;
  const size_t O_TOK    = 2048;
  const size_t O_W      = O_TOK + (size_t)NEXP * TOK * 4;            // 526336
  const size_t O_WGT    = O_W + (size_t)NEXP * TOK * 4;              // 1050624
  const size_t O_SEL    = O_WGT + (size_t)NEXP * DIM * 4;            // +32KB
  const size_t O_WP     = O_SEL + (size_t)TOK * 4;                   // +64KB
  const size_t O_W1S    = O_WP + (size_t)TOK * 8;                    // +128KB
  const size_t O_W2S    = O_W1S + (size_t)NEXP * 16 * 16 * 8192 * 2;    // +33.55MB
  const size_t O_XBF    = O_W2S + (size_t)NEXP * 8 * 32 * 8192 * 2;     // +33.55MB
  const size_t O_HS     = O_XBF + (size_t)TOK * DIM * 2;                // +33.55MB (~102MB)

  // largest H-chunk whose hs fits: hs = 34816 padded rows * Hc * 2 B
  int Hc = 0;
  if (ws_size > O_HS) {
    size_t avail = ws_size - O_HS;
    for (int hc = HID; hc >= 256; hc >>= 1)
      if ((size_t)34816 * hc * 2 <= avail) { Hc = hc; break; }
  }

  if (Hc) {
    int*   counts   = (int*)(ws + O_COUNTS);
    int*   offp     = (int*)(ws + O_OFF);
    int*   tok_list = (int*)(ws + O_TOK);
    float* w_list   = (float*)(ws + O_W);
    float* WgT      = (float*)(ws + O_WGT);
    int*   sel      = (int*)(ws + O_SEL);
    float2* wp      = (float2*)(ws + O_WP);
    unsigned short* w1s = (unsigned short*)(ws + O_W1S);
    unsigned short* w2s = (unsigned short*)(ws + O_W2S);
    unsigned short* xbf = (unsigned short*)(ws + O_XBF);
    unsigned short* hs  = (unsigned short*)(ws + O_HS);

    hipMemsetAsync(counts, 0, 2048, stream);
    wg_tr<<<32, 256, 0, stream>>>(Wg, WgT);
    prep_tiles<<<dim3(HID / 128, DIM / 64, NEXP), 256, 0, stream>>>(W1, w1s, DIM, HID);
    prep_tiles<<<dim3(DIM / 128, HID / 64, NEXP), 256, 0, stream>>>(W2, w2s, HID, DIM);
    router_logits_cvt<<<TOK / 4, 256, 0, stream>>>(x, WgT, xbf, sel, wp);
    router_scatter<<<TOK / 256, 256, 0, stream>>>(sel, wp, counts, tok_list, w_list);
    calc_off<<<1, 64, 0, stream>>>(counts, offp);

    int nch = HID / Hc, nkbc = Hc / 64, nct = Hc / 128;
    for (int ch = 0; ch < nch; ch++) {
      moe_gemm1<<<272 * nct, 256, 0, stream>>>(
          xbf, w1s, b1, counts, offp, tok_list, hs, ch * nct, nkbc, nct);
      for (int seg = 0; seg < 2; seg++) {
        int add_b2 = (ch == 0) ? 1 : 0;
        int accum  = (ch == 0 && seg == 0) ? 0 : 1;
        int kb_off = ch * nkbc;
        #define LG2(NK) moe_gemm2<NK><<<136 * 4, 256, 0, stream>>>( \
            hs, w2s, b2, counts, offp, tok_list, w_list, y, seg, kb_off, add_b2, accum)
        switch (nkbc) {
          case 32: LG2(32); break;
          case 16: LG2(16); break;
          case 8:  LG2(8);  break;
          default: LG2(4);  break;
        }
        #undef LG2
      }
    }
  } else {
    // legacy path (ws too small)
    int*   counts   = (int*)ws;
    int*   tok_list = (int*)(ws + 2048);
    float* w_list   = (float*)(ws + 2048 + (size_t)NEXP * TOK * 4);
    unsigned short* w1t = (unsigned short*)(ws + 2048 + (size_t)NEXP * TOK * 8);
    unsigned short* w2t = w1t + (size_t)NEXP * HID * DIM;

    hipMemsetAsync(d_out, 0, (size_t)out_size * sizeof(float), stream);
    hipMemsetAsync(counts, 0, 2048, stream);
    transpose_cvt<<<dim3(HID / 32, DIM / 32, NEXP), dim3(32, 8), 0, stream>>>(W1, w1t, DIM, HID);
    transpose_cvt<<<dim3(DIM / 32, HID / 32, NEXP), dim3(32, 8), 0, stream>>>(W2, w2t, HID, DIM);
    router_kernel<<<TOK / 4, 256, 0, stream>>>(x, Wg, counts, tok_list, w_list);
    moe_ffn_kernel<<<dim3(TOK / 32, 16), 512, 0, stream>>>(
        x, w1t, w2t, b1, b2, counts, tok_list, w_list, y);
  }
}

// Round 11
// 505.111 us; speedup vs baseline: 1.2569x; 1.1966x over previous
//
#include <hip/hip_runtime.h>
#include <hip/hip_bf16.h>

#define TOK 16384
#define DIM 1024
#define HID 2048
#define NEXP 8

typedef __attribute__((ext_vector_type(4))) float f32x4;
typedef __attribute__((ext_vector_type(8))) short s16x8;

__device__ __forceinline__ unsigned short f2bf(float f) {
  union { float f; unsigned u; } v; v.f = f;
  unsigned r = v.u + 0x7fffu + ((v.u >> 16) & 1u);   // RNE
  return (unsigned short)(r >> 16);
}
// byte offset of element (r, byte-col kk2) inside a [128 rows][128 B] tile, XOR-swizzled
__device__ __forceinline__ int tile_byte(int r, int kk2) {
  return (r * 128 + kk2) ^ ((r & 7) << 4);
}
__device__ __forceinline__ void gld_lds16(const void* g, void* l) {
  __builtin_amdgcn_global_load_lds(
      (const __attribute__((address_space(1))) unsigned int*)g,
      (__attribute__((address_space(3))) unsigned int*)l, 16, 0, 0);
}
// bijective XCD-chunked block remap (m204): physical p (xcd = p%8) -> logical
__device__ __forceinline__ int xcd_swz(int p, int nwg) {
  int q = nwg >> 3, r = nwg & 7;
  int xcd = p & 7, idx = p >> 3;
  return (xcd < r ? xcd * (q + 1) : r * (q + 1) + (xcd - r) * q) + idx;
}

// Wg [D][E] -> WgT [E][D] fp32 (tiny, 32 KB)
__global__ void wg_tr(const float* __restrict__ Wg, float* __restrict__ WgT) {
  int i = blockIdx.x * 256 + threadIdx.x;   // 8192
  int e = i >> 10, dd = i & 1023;
  WgT[i] = Wg[dd * NEXP + e];
}

// ---------------------------------------------------------------------------
// Weight prepass: fp32 src [E][rows][cols] -> bf16 128-wide tiled-swizzled
// dst[e][ct][kb][16KB tile]; tile(r<128, kk<64) = src[e][kb*64+kk][ct*128+r]
// ---------------------------------------------------------------------------
__global__ void prep_tiles(const float* __restrict__ src, unsigned short* __restrict__ dst,
                           int rows, int cols) {
  int ct = blockIdx.x, kb = blockIdx.y, e = blockIdx.z;
  int nct = gridDim.x, nkb = gridDim.y;
  __shared__ __align__(16) unsigned short tile[8192];
  const float* s = src + ((size_t)e * rows + kb * 64) * cols + ct * 128;
  int tid = threadIdx.x;  // 256
  #pragma unroll
  for (int it = 0; it < 8; it++) {
    int idx = it * 256 + tid;          // 2048 float4 chunks
    int kk = idx >> 5;                 // 0..63
    int r4 = (idx & 31) * 4;           // 0..124
    float4 v = *(const float4*)(s + (size_t)kk * cols + r4);
    char* tb = (char*)tile;
    *(unsigned short*)(tb + tile_byte(r4 + 0, kk * 2)) = f2bf(v.x);
    *(unsigned short*)(tb + tile_byte(r4 + 1, kk * 2)) = f2bf(v.y);
    *(unsigned short*)(tb + tile_byte(r4 + 2, kk * 2)) = f2bf(v.z);
    *(unsigned short*)(tb + tile_byte(r4 + 3, kk * 2)) = f2bf(v.w);
  }
  __syncthreads();
  unsigned short* d = dst + (((size_t)e * nct + ct) * nkb + kb) * 8192;
  #pragma unroll
  for (int it = 0; it < 4; it++) {
    int o = it * 256 + tid;
    *(s16x8*)(d + o * 8) = *(const s16x8*)((const char*)tile + o * 16);
  }
}

// ---------------------------------------------------------------------------
// Router phase A (fused x->bf16 convert): fp32 logits via coalesced WgT,
// exact top-2, no atomics.
// ---------------------------------------------------------------------------
__global__ __launch_bounds__(256)
void router_logits_cvt(const float* __restrict__ x, const float* __restrict__ WgT,
                       unsigned short* __restrict__ xbf,
                       int* __restrict__ sel, float2* __restrict__ wp) {
  int wave = threadIdx.x >> 6, lane = threadIdx.x & 63;
  int t = blockIdx.x * 4 + wave;
  const f32x4* xr = (const f32x4*)(x + (size_t)t * DIM);
  unsigned short* xb = xbf + (size_t)t * DIM;
  float acc[NEXP];
  #pragma unroll
  for (int e = 0; e < NEXP; e++) acc[e] = 0.f;
  #pragma unroll
  for (int q = 0; q < 4; q++) {
    f32x4 xv = xr[q * 64 + lane];
    ushort4 bv;
    bv.x = f2bf(xv[0]); bv.y = f2bf(xv[1]); bv.z = f2bf(xv[2]); bv.w = f2bf(xv[3]);
    *(ushort4*)(xb + (q * 64 + lane) * 4) = bv;
    #pragma unroll
    for (int e = 0; e < NEXP; e++) {
      f32x4 wv = *(const f32x4*)(WgT + (size_t)e * DIM + (q * 64 + lane) * 4);
      acc[e] = fmaf(xv[3], wv[3], fmaf(xv[2], wv[2], fmaf(xv[1], wv[1], fmaf(xv[0], wv[0], acc[e]))));
    }
  }
  #pragma unroll
  for (int e = 0; e < NEXP; e++) {
    float v = acc[e];
    #pragma unroll
    for (int off = 32; off >= 1; off >>= 1) v += __shfl_xor(v, off);
    acc[e] = v;
  }
  if (lane == 0) {
    float m = acc[0];
    #pragma unroll
    for (int e = 1; e < NEXP; e++) m = fmaxf(m, acc[e]);
    float p[NEXP], s = 0.f;
    #pragma unroll
    for (int e = 0; e < NEXP; e++) { p[e] = expf(acc[e] - m); s += p[e]; }
    float inv = 1.f / s;
    int i0 = 0; float v0 = p[0];
    #pragma unroll
    for (int e = 1; e < NEXP; e++) if (p[e] > v0) { v0 = p[e]; i0 = e; }   // strict > = low-index tie-break
    int i1 = -1; float v1 = -1.f;
    #pragma unroll
    for (int e = 0; e < NEXP; e++) if (e != i0 && p[e] > v1) { v1 = p[e]; i1 = e; }
    v0 *= inv; v1 *= inv;
    float den = v0 + v1 + 1e-9f;
    sel[t] = i0 | (i1 << 4);
    wp[t] = make_float2(v0 / den, v1 / den);
  }
}

// ---------------------------------------------------------------------------
// Router phase B: ballot-ranked scatter; 1 atomic per (block,bin).
// ---------------------------------------------------------------------------
__global__ __launch_bounds__(256)
void router_scatter(const int* __restrict__ sel, const float2* __restrict__ wp,
                    int* __restrict__ counts, int* __restrict__ tok_list,
                    float* __restrict__ w_list) {
  __shared__ int lh0[4][16], lh1[4][16];
  __shared__ int bbase[16];
  int tid = threadIdx.x, wave = tid >> 6, lane = tid & 63;
  int t = blockIdx.x * 256 + tid;
  int s = sel[t];
  int b0 = s & 15;
  int b1 = 8 + ((s >> 4) & 15);
  float2 w = wp[t];
  unsigned long long lt = (lane == 63) ? ~0ull >> 1 : (((unsigned long long)1 << lane) - 1);
  int r0 = 0, r1 = 0;
  #pragma unroll
  for (int b = 0; b < 8; b++) {
    unsigned long long m0 = __ballot(b0 == b);
    if (b0 == b) r0 = __popcll(m0 & lt);
    if (lane == 0) { lh0[wave][b] = __popcll(m0); lh1[wave][b] = 0; }
  }
  #pragma unroll
  for (int b = 8; b < 16; b++) {
    unsigned long long m1 = __ballot(b1 == b);
    if (b1 == b) r1 = __popcll(m1 & lt);
    if (lane == 0) { lh1[wave][b] = __popcll(m1); lh0[wave][b] = 0; }
  }
  __syncthreads();
  if (tid < 16) {
    int h = 0;
    #pragma unroll
    for (int v = 0; v < 4; v++) h += lh0[v][tid] + lh1[v][tid];
    bbase[tid] = atomicAdd(&counts[tid], h);
  }
  __syncthreads();
  int p0 = bbase[b0] + r0;
  int p1 = bbase[b1] + r1;
  #pragma unroll
  for (int v = 0; v < 4; v++) {
    if (v < wave) { p0 += lh0[v][b0]; p1 += lh1[v][b1]; }
  }
  int e0 = b0, e1 = b1 - 8;
  tok_list[e0 * TOK + p0] = t;
  w_list[e0 * TOK + p0] = w.x;
  int q1 = TOK - 1 - p1;
  tok_list[e1 * TOK + q1] = t;
  w_list[e1 * TOK + q1] = w.y;
}

// off[e*2+seg] = prefix of 128-padded segment row counts
__global__ void calc_off(const int* __restrict__ counts, int* __restrict__ off) {
  if (threadIdx.x == 0 && blockIdx.x == 0) {
    int a = 0;
    for (int e = 0; e < NEXP; e++)
      for (int s = 0; s < 2; s++) {
        off[e * 2 + s] = a;
        a += (counts[s * 8 + e] + 127) & ~127;
      }
  }
}

// ---------------------------------------------------------------------------
// GEMM1 (r7 winner + ct-half blocking): 128x128 tile, BK=64, 4 waves (2x2),
// single-buffer 32KB LDS, 2 barriers/K-step. Logical order per (e,seg):
// ct-half (8 cts = 2MB W1) -> row-tiles -> ct-within-half, so each XCD's L2
// working set = 2MB W1-half + 256KB xbf strip (was 4.25MB -> thrash).
// ---------------------------------------------------------------------------
__global__ __launch_bounds__(256, 4)
void moe_gemm1(const unsigned short* __restrict__ xbf, const unsigned short* __restrict__ w1s,
               const float* __restrict__ b1, const int* __restrict__ counts,
               const int* __restrict__ off, const int* __restrict__ tok_list,
               unsigned short* __restrict__ h_s, int ct_off, int nkbc, int nct) {
  int logical = xcd_swz(blockIdx.x, gridDim.x);
  int CG = (nct >= 8) ? 8 : nct;               // cts per locality group
  int e = -1, seg = 0, rt = 0, ct_l = 0, segcnt = 0, base = 0;
  #pragma unroll
  for (int zz = 0; zz < 16; zz++) {
    int ee = zz >> 1, ss = zz & 1;
    int c = counts[ss * 8 + ee];
    int nt = (c + 127) >> 7;
    int span = nt * nct;
    if (e < 0 && logical < base + span) {
      e = ee; seg = ss; segcnt = c;
      int local = logical - base;
      int grp = nt * CG;
      int h = local / grp, rem = local - h * grp;
      rt = rem / CG;
      ct_l = h * CG + (rem - rt * CG);
    }
    base += span;
  }
  if (e < 0) return;

  __shared__ __align__(16) unsigned short As[8192];
  __shared__ __align__(16) unsigned short Bs[8192];
  __shared__ int tokS[128];

  int tid = threadIdx.x, wave = tid >> 6, lane = tid & 63;
  int llo = lane & 15, lhi = lane >> 4;
  int wr = wave >> 1, wc = wave & 1;
  int ct_g = ct_off + ct_l;

  if (tid < 128) {
    int q = rt * 128 + tid;
    int qq = q < segcnt ? q : segcnt - 1;       // clamp: dup rows land in hs pad, discarded later
    int slot = seg ? (TOK - 1 - qq) : qq;
    tokS[tid] = tok_list[e * TOK + slot];
  }
  __syncthreads();

  // A sources: linear LDS chunk (i*256+tid) covers (row = i*32 + tid/8, c16 = tid&7);
  // source chunk pre-swizzled so swizzled ds_read gets original bytes (rule #21).
  const char* srcA[4];
  #pragma unroll
  for (int i = 0; i < 4; i++) {
    int r = i * 32 + (tid >> 3);
    srcA[i] = (const char*)xbf + (size_t)tokS[r] * (DIM * 2) + (((tid & 7) ^ (r & 7)) * 16);
  }
  const char* gB = (const char*)(w1s + (((size_t)e * 16 + ct_g) * 16) * 8192);

  f32x4 acc[4][4];
  #pragma unroll
  for (int i = 0; i < 4; i++)
    #pragma unroll
    for (int j = 0; j < 4; j++) acc[i][j] = (f32x4){0.f, 0.f, 0.f, 0.f};

  for (int kb = 0; kb < 16; kb++) {
    #pragma unroll
    for (int i = 0; i < 4; i++)
      gld_lds16(srcA[i] + kb * 128, (char*)As + i * 4096 + wave * 1024);
    const char* gs = gB + (size_t)kb * 16384 + wave * 1024 + lane * 16;
    #pragma unroll
    for (int i = 0; i < 4; i++)
      gld_lds16(gs + i * 4096, (char*)Bs + i * 4096 + wave * 1024);
    __syncthreads();
    #pragma unroll
    for (int ks = 0; ks < 2; ks++) {
      s16x8 a[4], b[4];
      #pragma unroll
      for (int f = 0; f < 4; f++) {
        a[f] = *(const s16x8*)((const char*)As + tile_byte(wr * 64 + f * 16 + llo, ks * 64 + lhi * 16));
        b[f] = *(const s16x8*)((const char*)Bs + tile_byte(wc * 64 + f * 16 + llo, ks * 64 + lhi * 16));
      }
      #pragma unroll
      for (int fr = 0; fr < 4; fr++)
        #pragma unroll
        for (int fc = 0; fc < 4; fc++)
          acc[fr][fc] = __builtin_amdgcn_mfma_f32_16x16x32_bf16(a[fr], b[fc], acc[fr][fc], 0, 0, 0);
    }
    __syncthreads();
  }

  // epilogue: relu(acc + b1) -> hs 128-tiled-swizzled bf16 (chunk-local tiles)
  size_t grt = (size_t)(off[e * 2 + seg] >> 7) + rt;
  unsigned short* hb = h_s + grt * ((size_t)nkbc * 8192);
  const float* b1e = b1 + e * HID + ct_g * 128;
  #pragma unroll
  for (int fc = 0; fc < 4; fc++) {
    int col = wc * 64 + fc * 16 + llo;        // 0..127 within ct
    float bv = b1e[col];
    char* tb = (char*)(hb + ((size_t)(ct_l * 2 + (col >> 6))) * 8192);
    int kk2 = (col & 63) * 2;
    #pragma unroll
    for (int fr = 0; fr < 4; fr++) {
      int r0 = wr * 64 + fr * 16 + lhi * 4;
      #pragma unroll
      for (int j = 0; j < 4; j++) {
        float v = fmaxf(acc[fr][fc][j] + bv, 0.f);
        *(unsigned short*)(tb + tile_byte(r0 + j, kk2)) = f2bf(v);
      }
    }
  }
}

// ---------------------------------------------------------------------------
// GEMM2 (r7 winner + ct-half blocking): y[t] (= | +=) w*(hs @ W2_chunk) [+w*b2].
// 128x128 tile, single-buffer 32KB LDS, 2 barriers/K-step. Logical order per
// (e,seg): ct-half (4 cts = 2MB W2) -> row-tiles -> ct-within-half, so each
// XCD's L2 working set = 2MB W2-half + 512KB hs strip (was 4.5MB -> thrash,
// ~6 TB/s L3 stream = the measured bottleneck).
// ---------------------------------------------------------------------------
template<int NKBC>
__global__ __launch_bounds__(256, 4)
void moe_gemm2(const unsigned short* __restrict__ h_s, const unsigned short* __restrict__ w2s,
               const float* __restrict__ b2, const int* __restrict__ counts,
               const int* __restrict__ off, const int* __restrict__ tok_list,
               const float* __restrict__ w_list, float* __restrict__ y,
               int seg, int kb_off, int add_b2, int accum) {
  int logical = xcd_swz(blockIdx.x, gridDim.x);
  int e = -1, rt = 0, ct = 0, segcnt = 0, base = 0;
  #pragma unroll
  for (int ee = 0; ee < 8; ee++) {
    int c = counts[seg * 8 + ee];
    int nt = (c + 127) >> 7;
    int span = nt * 8;
    if (e < 0 && logical < base + span) {
      e = ee; segcnt = c;
      int local = logical - base;
      int grp = nt * 4;
      int h = local / grp, rem = local - h * grp;
      rt = rem >> 2;
      ct = h * 4 + (rem & 3);
    }
    base += span;
  }
  if (e < 0) return;

  __shared__ __align__(16) unsigned short As[8192];
  __shared__ __align__(16) unsigned short Bs[8192];

  int tid = threadIdx.x, wave = tid >> 6, lane = tid & 63;
  int llo = lane & 15, lhi = lane >> 4;
  int wr = wave >> 1, wc = wave & 1;

  size_t grt = (size_t)(off[e * 2 + seg] >> 7) + rt;
  const char* gA = (const char*)(h_s + grt * ((size_t)NKBC * 8192));
  const char* gB = (const char*)(w2s + (((size_t)e * 8 + ct) * 32 + kb_off) * 8192);

  f32x4 acc[4][4];
  #pragma unroll
  for (int i = 0; i < 4; i++)
    #pragma unroll
    for (int j = 0; j < 4; j++) acc[i][j] = (f32x4){0.f, 0.f, 0.f, 0.f};

  for (int kb = 0; kb < NKBC; kb++) {
    const char* ga = gA + (size_t)kb * 16384 + wave * 1024 + lane * 16;
    const char* gb = gB + (size_t)kb * 16384 + wave * 1024 + lane * 16;
    #pragma unroll
    for (int i = 0; i < 4; i++) {
      gld_lds16(ga + i * 4096, (char*)As + i * 4096 + wave * 1024);
      gld_lds16(gb + i * 4096, (char*)Bs + i * 4096 + wave * 1024);
    }
    __syncthreads();
    #pragma unroll
    for (int ks = 0; ks < 2; ks++) {
      s16x8 a[4], b[4];
      #pragma unroll
      for (int f = 0; f < 4; f++) {
        a[f] = *(const s16x8*)((const char*)As + tile_byte(wr * 64 + f * 16 + llo, ks * 64 + lhi * 16));
        b[f] = *(const s16x8*)((const char*)Bs + tile_byte(wc * 64 + f * 16 + llo, ks * 64 + lhi * 16));
      }
      #pragma unroll
      for (int fr = 0; fr < 4; fr++)
        #pragma unroll
        for (int fc = 0; fc < 4; fc++)
          acc[fr][fc] = __builtin_amdgcn_mfma_f32_16x16x32_bf16(a[fr], b[fc], acc[fr][fc], 0, 0, 0);
    }
    __syncthreads();
  }

  const float* b2e = b2 + e * DIM + ct * 128;
  #pragma unroll
  for (int fr = 0; fr < 4; fr++) {
    #pragma unroll
    for (int j = 0; j < 4; j++) {
      int q = rt * 128 + wr * 64 + fr * 16 + lhi * 4 + j;
      if (q < segcnt) {
        int slot = seg ? (TOK - 1 - q) : q;
        int t = tok_list[e * TOK + slot];
        float w = w_list[e * TOK + slot];
        float bs = add_b2 ? w : 0.f;
        #pragma unroll
        for (int fc = 0; fc < 4; fc++) {
          int col = wc * 64 + fc * 16 + llo;
          float val = w * acc[fr][fc][j] + bs * b2e[col];
          size_t idx = (size_t)t * DIM + ct * 128 + col;
          if (accum) y[idx] += val;
          else       y[idx] = val;
        }
      }
    }
  }
}

// ======================= legacy fallback (round-1 style) ====================
__global__ void transpose_cvt(const float* __restrict__ src, unsigned short* __restrict__ dst,
                              int R, int C) {
  __shared__ float tile[32][33];
  int e = blockIdx.z;
  const float* s = src + (size_t)e * R * C;
  unsigned short* d = dst + (size_t)e * R * C;
  int c0 = blockIdx.x * 32, r0 = blockIdx.y * 32;
  int tx = threadIdx.x, ty = threadIdx.y;
  #pragma unroll
  for (int i = 0; i < 32; i += 8)
    tile[ty + i][tx] = s[(size_t)(r0 + ty + i) * C + c0 + tx];
  __syncthreads();
  #pragma unroll
  for (int i = 0; i < 32; i += 8)
    d[(size_t)(c0 + ty + i) * R + r0 + tx] = f2bf(tile[tx][ty + i]);
}

__global__ void router_kernel(const float* __restrict__ x, const float* __restrict__ Wg,
                              int* __restrict__ counts, int* __restrict__ tok_list,
                              float* __restrict__ w_list) {
  int wave = threadIdx.x >> 6, lane = threadIdx.x & 63;
  int t = blockIdx.x * 4 + wave;
  const float* xr = x + (size_t)t * DIM;
  float acc[NEXP];
  #pragma unroll
  for (int e = 0; e < NEXP; e++) acc[e] = 0.f;
  for (int i = 0; i < DIM / 64; i++) {
    int dd = i * 64 + lane;
    float xv = xr[dd];
    const float* wr = Wg + (size_t)dd * NEXP;
    #pragma unroll
    for (int e = 0; e < NEXP; e++) acc[e] = fmaf(xv, wr[e], acc[e]);
  }
  #pragma unroll
  for (int e = 0; e < NEXP; e++) {
    float v = acc[e];
    #pragma unroll
    for (int off = 32; off >= 1; off >>= 1) v += __shfl_xor(v, off);
    acc[e] = v;
  }
  if (lane == 0) {
    float m = acc[0];
    #pragma unroll
    for (int e = 1; e < NEXP; e++) m = fmaxf(m, acc[e]);
    float p[NEXP], s = 0.f;
    #pragma unroll
    for (int e = 0; e < NEXP; e++) { p[e] = expf(acc[e] - m); s += p[e]; }
    float inv = 1.f / s;
    int i0 = 0; float v0 = p[0];
    #pragma unroll
    for (int e = 1; e < NEXP; e++) if (p[e] > v0) { v0 = p[e]; i0 = e; }
    int i1 = -1; float v1 = -1.f;
    #pragma unroll
    for (int e = 0; e < NEXP; e++) if (e != i0 && p[e] > v1) { v1 = p[e]; i1 = e; }
    v0 *= inv; v1 *= inv;
    float den = v0 + v1 + 1e-9f;
    float w0 = v0 / den, w1 = v1 / den;
    int q0 = atomicAdd(&counts[i0], 1);
    tok_list[i0 * TOK + q0] = t;           w_list[i0 * TOK + q0] = w0;
    int q1 = atomicAdd(&counts[8 + i1], 1);
    int p1 = TOK - 1 - q1;
    tok_list[i1 * TOK + p1] = t;           w_list[i1 * TOK + p1] = w1;
  }
}

__global__ __launch_bounds__(512, 4)
void moe_ffn_kernel(const float* __restrict__ x,
                    const unsigned short* __restrict__ w1t,
                    const unsigned short* __restrict__ w2t,
                    const float* __restrict__ b1, const float* __restrict__ b2,
                    const int* __restrict__ counts, const int* __restrict__ tok_list,
                    const float* __restrict__ w_list, float* __restrict__ y) {
  int zz = blockIdx.y, e = zz & 7, seg = zz >> 3;
  int segcnt = counts[seg * 8 + e];
  int row0 = blockIdx.x * 32;
  if (row0 >= segcnt) return;
  __shared__ unsigned short Xs[32 * DIM];
  __shared__ unsigned short hsl[32 * 64];
  __shared__ int tokS[32];
  __shared__ float wS[32];
  int tid = threadIdx.x, wave = tid >> 6, lane = tid & 63;
  if (tid < 32) {
    int q = row0 + tid;
    if (q < segcnt) {
      int slot = seg ? (TOK - 1 - q) : q;
      tokS[tid] = tok_list[e * TOK + slot]; wS[tid] = w_list[e * TOK + slot];
    } else { tokS[tid] = -1; wS[tid] = 0.f; }
  }
  __syncthreads();
  #pragma unroll
  for (int it = 0; it < 8; it++) {
    int chunk = it * 512 + tid;
    int r = chunk >> 7, c = (chunk & 127) * 8;
    int tok = tokS[r];
    float4 f0 = make_float4(0.f, 0.f, 0.f, 0.f), f1 = f0;
    if (tok >= 0) {
      const float4* xp = (const float4*)(x + (size_t)tok * DIM + c);
      f0 = xp[0]; f1 = xp[1];
    }
    s16x8 bv;
    bv[0] = (short)f2bf(f0.x); bv[1] = (short)f2bf(f0.y);
    bv[2] = (short)f2bf(f0.z); bv[3] = (short)f2bf(f0.w);
    bv[4] = (short)f2bf(f1.x); bv[5] = (short)f2bf(f1.y);
    bv[6] = (short)f2bf(f1.z); bv[7] = (short)f2bf(f1.w);
    int byte = (r * DIM + c) * 2; byte ^= (r & 7) << 4;
    *(s16x8*)((char*)Xs + byte) = bv;
  }
  __syncthreads();
  int rw = wave >> 2, cw = wave & 3;
  int lhi = lane >> 4, llo = lane & 15;
  f32x4 acc[16];
  #pragma unroll
  for (int i = 0; i < 16; i++) acc[i] = (f32x4){0.f, 0.f, 0.f, 0.f};
  int arow = rw * 16 + llo;
  int abase = arow * (DIM * 2) + lhi * 16;
  int aswz = (arow & 7) << 4;
  int h_abase = arow * (64 * 2) + lhi * 16;
  const size_t eHD = (size_t)e * HID * DIM;
  const unsigned short* w2e = w2t + (size_t)e * DIM * HID;
  for (int hc = 0; hc < HID; hc += 64) {
    f32x4 c1 = (f32x4){0.f, 0.f, 0.f, 0.f};
    const unsigned short* w1p = w1t + eHD + (size_t)(hc + cw * 16 + llo) * DIM + lhi * 8;
    #pragma unroll 4
    for (int k = 0; k < DIM; k += 32) {
      s16x8 a = *(const s16x8*)((const char*)Xs + ((abase + k * 2) ^ aswz));
      s16x8 b = *(const s16x8*)(w1p + k);
      c1 = __builtin_amdgcn_mfma_f32_16x16x32_bf16(a, b, c1, 0, 0, 0);
    }
    float b1v = b1[e * HID + hc + cw * 16 + llo];
    __syncthreads();
    #pragma unroll
    for (int j = 0; j < 4; j++) {
      int r = rw * 16 + lhi * 4 + j;
      float v = fmaxf(c1[j] + b1v, 0.f);
      int byte = (r * 64 + cw * 16 + llo) * 2; byte ^= (r & 7) << 4;
      *(unsigned short*)((char*)hsl + byte) = f2bf(v);
    }
    __syncthreads();
    s16x8 a0 = *(const s16x8*)((const char*)hsl + ((h_abase + 0)  ^ aswz));
    s16x8 a1 = *(const s16x8*)((const char*)hsl + ((h_abase + 64) ^ aswz));
    const unsigned short* w2p0 = w2e + hc + lhi * 8;
    #pragma unroll 4
    for (int ctile = 0; ctile < 16; ctile++) {
      int dcol = cw * 256 + ctile * 16 + llo;
      const unsigned short* bp = w2p0 + (size_t)dcol * HID;
      s16x8 b0 = *(const s16x8*)(bp);
      s16x8 b1f = *(const s16x8*)(bp + 32);
      acc[ctile] = __builtin_amdgcn_mfma_f32_16x16x32_bf16(a0, b0, acc[ctile], 0, 0, 0);
      acc[ctile] = __builtin_amdgcn_mfma_f32_16x16x32_bf16(a1, b1f, acc[ctile], 0, 0, 0);
    }
  }
  const float* b2e = b2 + e * DIM;
  #pragma unroll
  for (int ctile = 0; ctile < 16; ctile++) {
    int dcol = cw * 256 + ctile * 16 + llo;
    float b2v = b2e[dcol];
    #pragma unroll
    for (int j = 0; j < 4; j++) {
      int r = rw * 16 + lhi * 4 + j;
      int tok = tokS[r];
      if (tok >= 0) atomicAdd(&y[(size_t)tok * DIM + dcol], wS[r] * (acc[ctile][j] + b2v));
    }
  }
}

// ===========================================================================
extern "C" void kernel_launch(void* const* d_in, const int* in_sizes, int n_in,
                              void* d_out, int out_size, void* d_ws, size_t ws_size,
                              hipStream_t stream) {
  const float* x  = (const float*)d_in[0];
  const float* Wg = (const float*)d_in[1];
  const float* W1 = (const float*)d_in[2];
  const float* b1 = (const float*)d_in[3];
  const float* W2 = (const float*)d_in[4];
  const float* b2 = (const float*)d_in[5];
  float* y = (float*)d_out;
  char* ws = (char*)d_ws;

  const size_t O_COUNTS = 0;
  const size_t O_OFF    = 1024;
  const size_t O_TOK    = 2048;
  const size_t O_W      = O_TOK + (size_t)NEXP * TOK * 4;            // 526336
  const size_t O_WGT    = O_W + (size_t)NEXP * TOK * 4;              // 1050624
  const size_t O_SEL    = O_WGT + (size_t)NEXP * DIM * 4;            // +32KB
  const size_t O_WP     = O_SEL + (size_t)TOK * 4;                   // +64KB
  const size_t O_W1S    = O_WP + (size_t)TOK * 8;                    // +128KB
  const size_t O_W2S    = O_W1S + (size_t)NEXP * 16 * 16 * 8192 * 2;    // +33.55MB
  const size_t O_XBF    = O_W2S + (size_t)NEXP * 8 * 32 * 8192 * 2;     // +33.55MB
  const size_t O_HS     = O_XBF + (size_t)TOK * DIM * 2;                // +33.55MB (~102MB)

  // largest H-chunk whose hs fits: hs = 34816 padded rows * Hc * 2 B
  int Hc = 0;
  if (ws_size > O_HS) {
    size_t avail = ws_size - O_HS;
    for (int hc = HID; hc >= 128; hc >>= 1)
      if ((size_t)34816 * hc * 2 <= avail) { Hc = hc; break; }
  }

  if (Hc) {
    int*   counts   = (int*)(ws + O_COUNTS);
    int*   offp     = (int*)(ws + O_OFF);
    int*   tok_list = (int*)(ws + O_TOK);
    float* w_list   = (float*)(ws + O_W);
    float* WgT      = (float*)(ws + O_WGT);
    int*   sel      = (int*)(ws + O_SEL);
    float2* wp      = (float2*)(ws + O_WP);
    unsigned short* w1s = (unsigned short*)(ws + O_W1S);
    unsigned short* w2s = (unsigned short*)(ws + O_W2S);
    unsigned short* xbf = (unsigned short*)(ws + O_XBF);
    unsigned short* hs  = (unsigned short*)(ws + O_HS);

    hipMemsetAsync(counts, 0, 2048, stream);
    wg_tr<<<32, 256, 0, stream>>>(Wg, WgT);
    prep_tiles<<<dim3(HID / 128, DIM / 64, NEXP), 256, 0, stream>>>(W1, w1s, DIM, HID);
    prep_tiles<<<dim3(DIM / 128, HID / 64, NEXP), 256, 0, stream>>>(W2, w2s, HID, DIM);
    router_logits_cvt<<<TOK / 4, 256, 0, stream>>>(x, WgT, xbf, sel, wp);
    router_scatter<<<TOK / 256, 256, 0, stream>>>(sel, wp, counts, tok_list, w_list);
    calc_off<<<1, 64, 0, stream>>>(counts, offp);

    int nch = HID / Hc, nkbc = Hc / 64, nct = Hc / 128;
    for (int ch = 0; ch < nch; ch++) {
      moe_gemm1<<<272 * nct, 256, 0, stream>>>(
          xbf, w1s, b1, counts, offp, tok_list, hs, ch * nct, nkbc, nct);
      for (int seg = 0; seg < 2; seg++) {
        int add_b2 = (ch == 0) ? 1 : 0;
        int accum  = (ch == 0 && seg == 0) ? 0 : 1;
        int kb_off = ch * nkbc;
        #define LG2(NK) moe_gemm2<NK><<<136 * 8, 256, 0, stream>>>( \
            hs, w2s, b2, counts, offp, tok_list, w_list, y, seg, kb_off, add_b2, accum)
        switch (nkbc) {
          case 32: LG2(32); break;
          case 16: LG2(16); break;
          case 8:  LG2(8);  break;
          case 4:  LG2(4);  break;
          default: LG2(2);  break;
        }
        #undef LG2
      }
    }
  } else {
    // legacy path (ws too small)
    int*   counts   = (int*)ws;
    int*   tok_list = (int*)(ws + 2048);
    float* w_list   = (float*)(ws + 2048 + (size_t)NEXP * TOK * 4);
    unsigned short* w1t = (unsigned short*)(ws + 2048 + (size_t)NEXP * TOK * 8);
    unsigned short* w2t = w1t + (size_t)NEXP * HID * DIM;

    hipMemsetAsync(d_out, 0, (size_t)out_size * sizeof(float), stream);
    hipMemsetAsync(counts, 0, 2048, stream);
    transpose_cvt<<<dim3(HID / 32, DIM / 32, NEXP), dim3(32, 8), 0, stream>>>(W1, w1t, DIM, HID);
    transpose_cvt<<<dim3(DIM / 32, HID / 32, NEXP), dim3(32, 8), 0, stream>>>(W2, w2t, HID, DIM);
    router_kernel<<<TOK / 4, 256, 0, stream>>>(x, Wg, counts, tok_list, w_list);
    moe_ffn_kernel<<<dim3(TOK / 32, 16), 512, 0, stream>>>(
        x, w1t, w2t, b1, b2, counts, tok_list, w_list, y);
  }
}